// Round 1
// baseline (2560.721 us; speedup 1.0000x reference)
//
#include <hip/hip_runtime.h>
#include <stdint.h>

// Grouped SwiGLU experts: out[g] = (silu(x@w1[e]) * (x@w3[e])) @ w2[e]
// g = b*8+e over B=4, E=8; per group M=2048 tokens, D=1024, F=2816. fp32 in/out.
//
// Round 1 changes vs round 0 (which measured 1873us; gemm_h=829us @912TF = m97
// structural ceiling, gemm_o ~800us @ ~470TF):
//  - T1 bijective XCD swizzle on both GEMMs: consecutive logical blocks (which
//    share the A panel) now land on the SAME XCD's L2 instead of round-robin
//    across 8 XCDs. Predicted: gemm_h FETCH 2.15GB -> ~1.2GB, gemm_o much less
//    HBM-pressured.
//  - __launch_bounds__(256,3): round 0 explicitly requested 2 blocks/CU
//    (Occupancy 23.5%); LDS 48KB allows 3 (144KB<160KB), VGPR=108 allows 4
//    waves/SIMD. 3 blocks/CU is the m97-reference occupancy that enables the
//    implicit MFMA||VMEM wave overlap (m114).

#define E_EXP 8
#define DM 1024
#define DF 2816
#define CTOK 2048
#define NGRP 32

typedef __attribute__((ext_vector_type(8))) __bf16 bf16x8;
typedef __attribute__((ext_vector_type(4))) float f32x4;

typedef __attribute__((address_space(1))) const void* as1_cvoid_p;
typedef __attribute__((address_space(3))) void* as3_void_p;

__device__ __forceinline__ void async_cp16(void* lds, const void* g) {
  __builtin_amdgcn_global_load_lds((as1_cvoid_p)g, (as3_void_p)lds, 16, 0, 0);
}

__device__ __forceinline__ unsigned short f2bf(float f) {
  union { float f; unsigned u; } v; v.f = f;
  unsigned u = v.u + 0x7fffu + ((v.u >> 16) & 1u);
  return (unsigned short)(u >> 16);
}

// Bijective XCD-aware remap (T1). HW assigns block hw_id to XCD hw_id%8; we
// give each XCD a CONTIGUOUS chunk of the logical (x-fastest) tile order so
// blocks sharing an A panel sit on one XCD's L2. Valid iff nwg%8==0
// (nx*ny = 352 or 128, both %8==0, for any gc).
__device__ __forceinline__ void xcd_remap(int& bx, int& by, int& bz) {
  const int nx = gridDim.x, ny = gridDim.y;
  const int nwg = nx * ny * gridDim.z;
  const int lin = blockIdx.x + nx * (blockIdx.y + ny * blockIdx.z);
  const int lid = (lin & 7) * (nwg >> 3) + (lin >> 3);
  const int pg = nx * ny;
  bz = lid / pg;
  const int rem = lid - bz * pg;
  by = rem / nx;
  bx = rem - by * nx;
}

// ---------------- prepass kernels ----------------

__global__ void convert_x_kernel(const float* __restrict__ in,
                                 unsigned short* __restrict__ out, size_t n) {
  size_t i = ((size_t)blockIdx.x * blockDim.x + threadIdx.x) * 8;
  float4 a = *(const float4*)(in + i);
  float4 b = *(const float4*)(in + i + 4);
  unsigned short r[8];
  r[0] = f2bf(a.x); r[1] = f2bf(a.y); r[2] = f2bf(a.z); r[3] = f2bf(a.w);
  r[4] = f2bf(b.x); r[5] = f2bf(b.y); r[6] = f2bf(b.z); r[7] = f2bf(b.w);
  *(uint4*)(out + i) = *(const uint4*)r;
}

// in: [E][R][C] fp32 row-major -> out: [E][C][R] bf16
__global__ void transpose_w_kernel(const float* __restrict__ in,
                                   unsigned short* __restrict__ out,
                                   int R, int C) {
  __shared__ float tile[32][33];
  const int e = blockIdx.z;
  in  += (size_t)e * R * C;
  out += (size_t)e * R * C;
  const int c0 = blockIdx.x * 32, r0 = blockIdx.y * 32;
  const int tc = threadIdx.x & 31, tr = threadIdx.x >> 5;  // 32 x 8
  #pragma unroll
  for (int i = 0; i < 32; i += 8)
    tile[tr + i][tc] = in[(size_t)(r0 + tr + i) * C + c0 + tc];
  __syncthreads();
  #pragma unroll
  for (int i = 0; i < 32; i += 8)
    out[(size_t)(c0 + tr + i) * R + r0 + tc] = f2bf(tile[tc][tr + i]);
}

// ---------------- fused gate/up GEMM ----------------
// h[g][m][f] = silu(sum_k x[m][k] w1t[f][k]) * (sum_k x[m][k] w3t[f][k])

__global__ void __launch_bounds__(256, 3) gemm_h_kernel(
    const unsigned short* __restrict__ xb,
    const unsigned short* __restrict__ w1t,
    const unsigned short* __restrict__ w3t,
    unsigned short* __restrict__ hbuf,
    int g0) {
  const int K = DM, F = DF, M = CTOK;
  int bx, by, bz;
  xcd_remap(bx, by, bz);
  const int gz = bz;
  const int g = g0 + gz;
  const int e = g & (E_EXP - 1);

  const unsigned short* A  = xb  + (size_t)g * M * K;
  const unsigned short* B1 = w1t + (size_t)e * F * K;
  const unsigned short* B3 = w3t + (size_t)e * F * K;
  unsigned short* hg = hbuf + (size_t)gz * M * F;

  const int m0 = by * 128;
  const int n0 = bx * 128;

  __shared__ __align__(16) union {
    struct { unsigned short A[128 * 64], B1[128 * 64], B3[128 * 64]; } t;
    unsigned short hs[128 * 136];
  } sm;

  const int tid = threadIdx.x;
  const int w = tid >> 6, L = tid & 63;
  const int wm = w >> 1, wn = w & 1;

  // staging: wave covers rows w*32..w*32+31 in 4 groups of 8; lane L -> row +L/8,
  // global 16B chunk (L&7)^(row&7) so LDS chunk c holds global chunk c^(row&7).
  const int srow = L >> 3;
  const int cs = (L & 7) ^ (srow & 7);
  int offA[4], offB[4];
  #pragma unroll
  for (int i = 0; i < 4; ++i) {
    const int r = w * 32 + i * 8 + srow;
    offA[i] = (m0 + r) * K + cs * 8;
    offB[i] = (n0 + r) * K + cs * 8;
  }

  f32x4 accg[4][4] = {};
  f32x4 accu[4][4] = {};

  const int rb = L & 15;
  const int q = L >> 4;
  const int x7 = L & 7;

  for (int kk = 0; kk < K; kk += 64) {
    #pragma unroll
    for (int i = 0; i < 4; ++i) {
      const int lr = (w * 32 + i * 8) * 64;
      async_cp16(&sm.t.A[lr],  A  + offA[i] + kk);
      async_cp16(&sm.t.B1[lr], B1 + offB[i] + kk);
      async_cp16(&sm.t.B3[lr], B3 + offB[i] + kk);
    }
    __syncthreads();

    #pragma unroll
    for (int s = 0; s < 2; ++s) {
      const int ch = ((s * 4 + q) ^ x7) * 8;  // un-swizzle on read
      bf16x8 af[4], b1f[4], b3f[4];
      #pragma unroll
      for (int t = 0; t < 4; ++t) {
        af[t]  = *(const bf16x8*)&sm.t.A [(wm * 64 + t * 16 + rb) * 64 + ch];
        b1f[t] = *(const bf16x8*)&sm.t.B1[(wn * 64 + t * 16 + rb) * 64 + ch];
        b3f[t] = *(const bf16x8*)&sm.t.B3[(wn * 64 + t * 16 + rb) * 64 + ch];
      }
      #pragma unroll
      for (int tm = 0; tm < 4; ++tm)
        #pragma unroll
        for (int tn = 0; tn < 4; ++tn) {
          accg[tm][tn] = __builtin_amdgcn_mfma_f32_16x16x32_bf16(
              af[tm], b1f[tn], accg[tm][tn], 0, 0, 0);
          accu[tm][tn] = __builtin_amdgcn_mfma_f32_16x16x32_bf16(
              af[tm], b3f[tn], accu[tm][tn], 0, 0, 0);
        }
    }
    __syncthreads();
  }

  // epilogue: silu(g)*u, bf16, repack via LDS for coalesced 16B stores.
  // C/D layout: row=(lane>>4)*4+reg, col=lane&15 within each 16x16 tile.
  #pragma unroll
  for (int tm = 0; tm < 4; ++tm)
    #pragma unroll
    for (int tn = 0; tn < 4; ++tn)
      #pragma unroll
      for (int r = 0; r < 4; ++r) {
        const int row = wm * 64 + tm * 16 + q * 4 + r;
        const int col = wn * 64 + tn * 16 + rb;
        const float gv = accg[tm][tn][r];
        const float uv = accu[tm][tn][r];
        const float hv = gv / (1.0f + __expf(-gv)) * uv;
        sm.hs[row * 136 + col] = f2bf(hv);
      }
  __syncthreads();
  #pragma unroll
  for (int p = 0; p < 8; ++p) {
    const int idx = p * 256 + tid;  // 2048 chunks of 16B
    const int row = idx >> 4;
    const int c16 = idx & 15;
    const uint4 v = *(const uint4*)&sm.hs[row * 136 + c16 * 8];
    *(uint4*)&hg[(size_t)(m0 + row) * F + n0 + c16 * 8] = v;
  }
}

// ---------------- down-proj GEMM ----------------
// out[g][m][d] = sum_f h[m][f] * w2t[d][f], fp32 out

__global__ void __launch_bounds__(256, 3) gemm_o_kernel(
    const unsigned short* __restrict__ hbuf,
    const unsigned short* __restrict__ w2t,
    float* __restrict__ out,
    int g0) {
  const int K = DF, N = DM, M = CTOK;
  int bx, by, bz;
  xcd_remap(bx, by, bz);
  const int gz = bz;
  const int g = g0 + gz;
  const int e = g & (E_EXP - 1);

  const unsigned short* A = hbuf + (size_t)gz * M * K;
  const unsigned short* B = w2t + (size_t)e * N * K;
  float* og = out + (size_t)g * M * N;

  const int m0 = by * 128;
  const int n0 = bx * 128;

  __shared__ __align__(16) unsigned short sA[128 * 64];
  __shared__ __align__(16) unsigned short sB[128 * 64];

  const int tid = threadIdx.x;
  const int w = tid >> 6, L = tid & 63;
  const int wm = w >> 1, wn = w & 1;

  const int srow = L >> 3;
  const int cs = (L & 7) ^ (srow & 7);
  int offA[4], offB[4];
  #pragma unroll
  for (int i = 0; i < 4; ++i) {
    const int r = w * 32 + i * 8 + srow;
    offA[i] = (m0 + r) * K + cs * 8;
    offB[i] = (n0 + r) * K + cs * 8;
  }

  f32x4 acc[4][4] = {};
  const int rb = L & 15;
  const int q = L >> 4;
  const int x7 = L & 7;

  for (int kk = 0; kk < K; kk += 64) {
    #pragma unroll
    for (int i = 0; i < 4; ++i) {
      const int lr = (w * 32 + i * 8) * 64;
      async_cp16(&sA[lr], A + offA[i] + kk);
      async_cp16(&sB[lr], B + offB[i] + kk);
    }
    __syncthreads();

    #pragma unroll
    for (int s = 0; s < 2; ++s) {
      const int ch = ((s * 4 + q) ^ x7) * 8;
      bf16x8 af[4], bf[4];
      #pragma unroll
      for (int t = 0; t < 4; ++t) {
        af[t] = *(const bf16x8*)&sA[(wm * 64 + t * 16 + rb) * 64 + ch];
        bf[t] = *(const bf16x8*)&sB[(wn * 64 + t * 16 + rb) * 64 + ch];
      }
      #pragma unroll
      for (int tm = 0; tm < 4; ++tm)
        #pragma unroll
        for (int tn = 0; tn < 4; ++tn)
          acc[tm][tn] = __builtin_amdgcn_mfma_f32_16x16x32_bf16(
              af[tm], bf[tn], acc[tm][tn], 0, 0, 0);
    }
    __syncthreads();
  }

  #pragma unroll
  for (int tm = 0; tm < 4; ++tm)
    #pragma unroll
    for (int tn = 0; tn < 4; ++tn)
      #pragma unroll
      for (int r = 0; r < 4; ++r) {
        const int row = wm * 64 + tm * 16 + q * 4 + r;
        const int col = wn * 64 + tn * 16 + rb;
        og[(size_t)(m0 + row) * N + n0 + col] = acc[tm][tn][r];
      }
}

// ---------------- launch ----------------

extern "C" void kernel_launch(void* const* d_in, const int* in_sizes, int n_in,
                              void* d_out, int out_size, void* d_ws, size_t ws_size,
                              hipStream_t stream) {
  const float* x  = (const float*)d_in[0];
  const float* w1 = (const float*)d_in[1];
  const float* w3 = (const float*)d_in[2];
  const float* w2 = (const float*)d_in[3];
  float* out = (float*)d_out;

  char* ws = (char*)d_ws;
  const size_t NX = (size_t)NGRP * CTOK * DM;     // 67108864 elements
  const size_t SX = NX * 2;                       // xb bytes
  const size_t SW = (size_t)E_EXP * DF * DM * 2;  // one transposed weight, bytes
  unsigned short* xb  = (unsigned short*)(ws);
  unsigned short* w1t = (unsigned short*)(ws + SX);
  unsigned short* w3t = (unsigned short*)(ws + SX + SW);
  unsigned short* w2t = (unsigned short*)(ws + SX + 2 * SW);
  unsigned short* hb  = (unsigned short*)(ws + SX + 3 * SW);

  const size_t fixed = SX + 3 * SW;
  const size_t per_g = (size_t)CTOK * DF * 2;  // h bytes per group
  int G = NGRP;
  if (ws_size < fixed + (size_t)NGRP * per_g) {
    size_t avail = ws_size > fixed ? ws_size - fixed : 0;
    G = (int)(avail / per_g);
    if (G < 1) G = 1;
    if (G > NGRP) G = NGRP;
  }

  convert_x_kernel<<<dim3((unsigned)(NX / 2048)), 256, 0, stream>>>(x, xb, NX);
  transpose_w_kernel<<<dim3(DF / 32, DM / 32, E_EXP), 256, 0, stream>>>(w1, w1t, DM, DF);
  transpose_w_kernel<<<dim3(DF / 32, DM / 32, E_EXP), 256, 0, stream>>>(w3, w3t, DM, DF);
  transpose_w_kernel<<<dim3(DM / 32, DF / 32, E_EXP), 256, 0, stream>>>(w2, w2t, DF, DM);

  for (int g0 = 0; g0 < NGRP; g0 += G) {
    const int gc = (NGRP - g0) < G ? (NGRP - g0) : G;
    gemm_h_kernel<<<dim3(DF / 128, CTOK / 128, gc), 256, 0, stream>>>(xb, w1t, w3t, hb, g0);
    gemm_o_kernel<<<dim3(DM / 128, CTOK / 128, gc), 256, 0, stream>>>(hb, w2t, out, g0);
  }
}

// Round 2
// 1771.818 us; speedup vs baseline: 1.4453x; 1.4453x over previous
//
#include <hip/hip_runtime.h>
#include <stdint.h>

// Grouped SwiGLU experts: out[g] = (silu(x@w1[e]) * (x@w3[e])) @ w2[e]
// g = b*8+e over B=4, E=8; per group M=2048 tokens, D=1024, F=2816. fp32 in/out.
//
// Round 2: round-0 structure (launch_bounds(256,2), VGPR=108, no spills)
// + T1 bijective XCD remap ONLY.
// Round-1 post-mortem: (256,3) forced VGPR 108->84 -> scratch spills
// (FETCH +1.2GB, WRITE +330MB of scratch traffic, MfmaUtil 42->19.5).
// NEVER squeeze below ~108 VGPR for this K-loop (32 acc + 48 frag regs live).

#define E_EXP 8
#define DM 1024
#define DF 2816
#define CTOK 2048
#define NGRP 32

typedef __attribute__((ext_vector_type(8))) __bf16 bf16x8;
typedef __attribute__((ext_vector_type(4))) float f32x4;

typedef __attribute__((address_space(1))) const void* as1_cvoid_p;
typedef __attribute__((address_space(3))) void* as3_void_p;

__device__ __forceinline__ void async_cp16(void* lds, const void* g) {
  __builtin_amdgcn_global_load_lds((as1_cvoid_p)g, (as3_void_p)lds, 16, 0, 0);
}

__device__ __forceinline__ unsigned short f2bf(float f) {
  union { float f; unsigned u; } v; v.f = f;
  unsigned u = v.u + 0x7fffu + ((v.u >> 16) & 1u);
  return (unsigned short)(u >> 16);
}

// Bijective XCD-aware remap (T1). HW assigns block hw_id to XCD hw_id%8; give
// each XCD a CONTIGUOUS chunk of the logical (x-fastest) tile order so blocks
// sharing an A panel sit on one XCD's L2. Valid iff nwg%8==0 (nx*ny is 352 or
// 128, both %8==0, for any gc).
__device__ __forceinline__ void xcd_remap(int& bx, int& by, int& bz) {
  const int nx = gridDim.x, ny = gridDim.y;
  const int nwg = nx * ny * gridDim.z;
  const int lin = blockIdx.x + nx * (blockIdx.y + ny * blockIdx.z);
  const int lid = (lin & 7) * (nwg >> 3) + (lin >> 3);
  const int pg = nx * ny;
  bz = lid / pg;
  const int rem = lid - bz * pg;
  by = rem / nx;
  bx = rem - by * nx;
}

// ---------------- prepass kernels ----------------

__global__ void convert_x_kernel(const float* __restrict__ in,
                                 unsigned short* __restrict__ out, size_t n) {
  size_t i = ((size_t)blockIdx.x * blockDim.x + threadIdx.x) * 8;
  float4 a = *(const float4*)(in + i);
  float4 b = *(const float4*)(in + i + 4);
  unsigned short r[8];
  r[0] = f2bf(a.x); r[1] = f2bf(a.y); r[2] = f2bf(a.z); r[3] = f2bf(a.w);
  r[4] = f2bf(b.x); r[5] = f2bf(b.y); r[6] = f2bf(b.z); r[7] = f2bf(b.w);
  *(uint4*)(out + i) = *(const uint4*)r;
}

// in: [E][R][C] fp32 row-major -> out: [E][C][R] bf16
__global__ void transpose_w_kernel(const float* __restrict__ in,
                                   unsigned short* __restrict__ out,
                                   int R, int C) {
  __shared__ float tile[32][33];
  const int e = blockIdx.z;
  in  += (size_t)e * R * C;
  out += (size_t)e * R * C;
  const int c0 = blockIdx.x * 32, r0 = blockIdx.y * 32;
  const int tc = threadIdx.x & 31, tr = threadIdx.x >> 5;  // 32 x 8
  #pragma unroll
  for (int i = 0; i < 32; i += 8)
    tile[tr + i][tc] = in[(size_t)(r0 + tr + i) * C + c0 + tc];
  __syncthreads();
  #pragma unroll
  for (int i = 0; i < 32; i += 8)
    out[(size_t)(c0 + tr + i) * R + r0 + tc] = f2bf(tile[tc][tr + i]);
}

// ---------------- fused gate/up GEMM ----------------
// h[g][m][f] = silu(sum_k x[m][k] w1t[f][k]) * (sum_k x[m][k] w3t[f][k])

__global__ void __launch_bounds__(256, 2) gemm_h_kernel(
    const unsigned short* __restrict__ xb,
    const unsigned short* __restrict__ w1t,
    const unsigned short* __restrict__ w3t,
    unsigned short* __restrict__ hbuf,
    int g0) {
  const int K = DM, F = DF, M = CTOK;
  int bx, by, bz;
  xcd_remap(bx, by, bz);
  const int gz = bz;
  const int g = g0 + gz;
  const int e = g & (E_EXP - 1);

  const unsigned short* A  = xb  + (size_t)g * M * K;
  const unsigned short* B1 = w1t + (size_t)e * F * K;
  const unsigned short* B3 = w3t + (size_t)e * F * K;
  unsigned short* hg = hbuf + (size_t)gz * M * F;

  const int m0 = by * 128;
  const int n0 = bx * 128;

  __shared__ __align__(16) union {
    struct { unsigned short A[128 * 64], B1[128 * 64], B3[128 * 64]; } t;
    unsigned short hs[128 * 136];
  } sm;

  const int tid = threadIdx.x;
  const int w = tid >> 6, L = tid & 63;
  const int wm = w >> 1, wn = w & 1;

  // staging: wave covers rows w*32..w*32+31 in 4 groups of 8; lane L -> row +L/8,
  // global 16B chunk (L&7)^(row&7) so LDS chunk c holds global chunk c^(row&7).
  const int srow = L >> 3;
  const int cs = (L & 7) ^ (srow & 7);
  int offA[4], offB[4];
  #pragma unroll
  for (int i = 0; i < 4; ++i) {
    const int r = w * 32 + i * 8 + srow;
    offA[i] = (m0 + r) * K + cs * 8;
    offB[i] = (n0 + r) * K + cs * 8;
  }

  f32x4 accg[4][4] = {};
  f32x4 accu[4][4] = {};

  const int rb = L & 15;
  const int q = L >> 4;
  const int x7 = L & 7;

  for (int kk = 0; kk < K; kk += 64) {
    #pragma unroll
    for (int i = 0; i < 4; ++i) {
      const int lr = (w * 32 + i * 8) * 64;
      async_cp16(&sm.t.A[lr],  A  + offA[i] + kk);
      async_cp16(&sm.t.B1[lr], B1 + offB[i] + kk);
      async_cp16(&sm.t.B3[lr], B3 + offB[i] + kk);
    }
    __syncthreads();

    #pragma unroll
    for (int s = 0; s < 2; ++s) {
      const int ch = ((s * 4 + q) ^ x7) * 8;  // un-swizzle on read
      bf16x8 af[4], b1f[4], b3f[4];
      #pragma unroll
      for (int t = 0; t < 4; ++t) {
        af[t]  = *(const bf16x8*)&sm.t.A [(wm * 64 + t * 16 + rb) * 64 + ch];
        b1f[t] = *(const bf16x8*)&sm.t.B1[(wn * 64 + t * 16 + rb) * 64 + ch];
        b3f[t] = *(const bf16x8*)&sm.t.B3[(wn * 64 + t * 16 + rb) * 64 + ch];
      }
      #pragma unroll
      for (int tm = 0; tm < 4; ++tm)
        #pragma unroll
        for (int tn = 0; tn < 4; ++tn) {
          accg[tm][tn] = __builtin_amdgcn_mfma_f32_16x16x32_bf16(
              af[tm], b1f[tn], accg[tm][tn], 0, 0, 0);
          accu[tm][tn] = __builtin_amdgcn_mfma_f32_16x16x32_bf16(
              af[tm], b3f[tn], accu[tm][tn], 0, 0, 0);
        }
    }
    __syncthreads();
  }

  // epilogue: silu(g)*u, bf16, repack via LDS for coalesced 16B stores.
  // C/D layout: row=(lane>>4)*4+reg, col=lane&15 within each 16x16 tile.
  #pragma unroll
  for (int tm = 0; tm < 4; ++tm)
    #pragma unroll
    for (int tn = 0; tn < 4; ++tn)
      #pragma unroll
      for (int r = 0; r < 4; ++r) {
        const int row = wm * 64 + tm * 16 + q * 4 + r;
        const int col = wn * 64 + tn * 16 + rb;
        const float gv = accg[tm][tn][r];
        const float uv = accu[tm][tn][r];
        const float hv = gv / (1.0f + __expf(-gv)) * uv;
        sm.hs[row * 136 + col] = f2bf(hv);
      }
  __syncthreads();
  #pragma unroll
  for (int p = 0; p < 8; ++p) {
    const int idx = p * 256 + tid;  // 2048 chunks of 16B
    const int row = idx >> 4;
    const int c16 = idx & 15;
    const uint4 v = *(const uint4*)&sm.hs[row * 136 + c16 * 8];
    *(uint4*)&hg[(size_t)(m0 + row) * F + n0 + c16 * 8] = v;
  }
}

// ---------------- down-proj GEMM ----------------
// out[g][m][d] = sum_f h[m][f] * w2t[d][f], fp32 out

__global__ void __launch_bounds__(256, 2) gemm_o_kernel(
    const unsigned short* __restrict__ hbuf,
    const unsigned short* __restrict__ w2t,
    float* __restrict__ out,
    int g0) {
  const int K = DF, N = DM, M = CTOK;
  int bx, by, bz;
  xcd_remap(bx, by, bz);
  const int gz = bz;
  const int g = g0 + gz;
  const int e = g & (E_EXP - 1);

  const unsigned short* A = hbuf + (size_t)gz * M * K;
  const unsigned short* B = w2t + (size_t)e * N * K;
  float* og = out + (size_t)g * M * N;

  const int m0 = by * 128;
  const int n0 = bx * 128;

  __shared__ __align__(16) unsigned short sA[128 * 64];
  __shared__ __align__(16) unsigned short sB[128 * 64];

  const int tid = threadIdx.x;
  const int w = tid >> 6, L = tid & 63;
  const int wm = w >> 1, wn = w & 1;

  const int srow = L >> 3;
  const int cs = (L & 7) ^ (srow & 7);
  int offA[4], offB[4];
  #pragma unroll
  for (int i = 0; i < 4; ++i) {
    const int r = w * 32 + i * 8 + srow;
    offA[i] = (m0 + r) * K + cs * 8;
    offB[i] = (n0 + r) * K + cs * 8;
  }

  f32x4 acc[4][4] = {};
  const int rb = L & 15;
  const int q = L >> 4;
  const int x7 = L & 7;

  for (int kk = 0; kk < K; kk += 64) {
    #pragma unroll
    for (int i = 0; i < 4; ++i) {
      const int lr = (w * 32 + i * 8) * 64;
      async_cp16(&sA[lr], A + offA[i] + kk);
      async_cp16(&sB[lr], B + offB[i] + kk);
    }
    __syncthreads();

    #pragma unroll
    for (int s = 0; s < 2; ++s) {
      const int ch = ((s * 4 + q) ^ x7) * 8;
      bf16x8 af[4], bf[4];
      #pragma unroll
      for (int t = 0; t < 4; ++t) {
        af[t] = *(const bf16x8*)&sA[(wm * 64 + t * 16 + rb) * 64 + ch];
        bf[t] = *(const bf16x8*)&sB[(wn * 64 + t * 16 + rb) * 64 + ch];
      }
      #pragma unroll
      for (int tm = 0; tm < 4; ++tm)
        #pragma unroll
        for (int tn = 0; tn < 4; ++tn)
          acc[tm][tn] = __builtin_amdgcn_mfma_f32_16x16x32_bf16(
              af[tm], bf[tn], acc[tm][tn], 0, 0, 0);
    }
    __syncthreads();
  }

  #pragma unroll
  for (int tm = 0; tm < 4; ++tm)
    #pragma unroll
    for (int tn = 0; tn < 4; ++tn)
      #pragma unroll
      for (int r = 0; r < 4; ++r) {
        const int row = wm * 64 + tm * 16 + q * 4 + r;
        const int col = wn * 64 + tn * 16 + rb;
        og[(size_t)(m0 + row) * N + n0 + col] = acc[tm][tn][r];
      }
}

// ---------------- launch ----------------

extern "C" void kernel_launch(void* const* d_in, const int* in_sizes, int n_in,
                              void* d_out, int out_size, void* d_ws, size_t ws_size,
                              hipStream_t stream) {
  const float* x  = (const float*)d_in[0];
  const float* w1 = (const float*)d_in[1];
  const float* w3 = (const float*)d_in[2];
  const float* w2 = (const float*)d_in[3];
  float* out = (float*)d_out;

  char* ws = (char*)d_ws;
  const size_t NX = (size_t)NGRP * CTOK * DM;     // 67108864 elements
  const size_t SX = NX * 2;                       // xb bytes
  const size_t SW = (size_t)E_EXP * DF * DM * 2;  // one transposed weight, bytes
  unsigned short* xb  = (unsigned short*)(ws);
  unsigned short* w1t = (unsigned short*)(ws + SX);
  unsigned short* w3t = (unsigned short*)(ws + SX + SW);
  unsigned short* w2t = (unsigned short*)(ws + SX + 2 * SW);
  unsigned short* hb  = (unsigned short*)(ws + SX + 3 * SW);

  const size_t fixed = SX + 3 * SW;
  const size_t per_g = (size_t)CTOK * DF * 2;  // h bytes per group
  int G = NGRP;
  if (ws_size < fixed + (size_t)NGRP * per_g) {
    size_t avail = ws_size > fixed ? ws_size - fixed : 0;
    G = (int)(avail / per_g);
    if (G < 1) G = 1;
    if (G > NGRP) G = NGRP;
  }

  convert_x_kernel<<<dim3((unsigned)(NX / 2048)), 256, 0, stream>>>(x, xb, NX);
  transpose_w_kernel<<<dim3(DF / 32, DM / 32, E_EXP), 256, 0, stream>>>(w1, w1t, DM, DF);
  transpose_w_kernel<<<dim3(DF / 32, DM / 32, E_EXP), 256, 0, stream>>>(w3, w3t, DM, DF);
  transpose_w_kernel<<<dim3(DM / 32, DF / 32, E_EXP), 256, 0, stream>>>(w2, w2t, DF, DM);

  for (int g0 = 0; g0 < NGRP; g0 += G) {
    const int gc = (NGRP - g0) < G ? (NGRP - g0) : G;
    gemm_h_kernel<<<dim3(DF / 128, CTOK / 128, gc), 256, 0, stream>>>(xb, w1t, w3t, hb, g0);
    gemm_o_kernel<<<dim3(DM / 128, CTOK / 128, gc), 256, 0, stream>>>(hb, w2t, out, g0);
  }
}